// Round 2
// baseline (1606.921 us; speedup 1.0000x reference)
//
#include <hip/hip_runtime.h>
#include <math.h>

#define DD    256
#define D3    768
#define KXC   512
#define MAXT  1000
#define BM    64
#define NTHR  512
#define SMEM_BYTES 147456   // A_hi 64K | A_lo 64K | H_hi 8K | H_lo 8K

using s16x8 = __attribute__((ext_vector_type(8))) short;
using f32x4 = __attribute__((ext_vector_type(4))) float;
using u16x4 = __attribute__((ext_vector_type(4))) unsigned short;

__device__ __forceinline__ unsigned short f2bf(float f) {
    union { float f; unsigned u; } v; v.f = f;
    unsigned r = v.u + 0x7fffu + ((v.u >> 16) & 1u);
    return (unsigned short)(r >> 16);
}
__device__ __forceinline__ float bf2f(unsigned short h) {
    union { unsigned u; float f; } v; v.u = ((unsigned)h) << 16;
    return v.f;
}

// ---------- timestep embedding table: Temb[1000][256] ----------
__global__ void k_temb(const float* __restrict__ Wstep, const float* __restrict__ bstep,
                       float* __restrict__ Temb) {
    __shared__ float emb[DD];
    const int tt  = blockIdx.x;
    const int tid = threadIdx.x;
    if (tid < 128) {
        const float nl = -9.210340371976184f;            // -ln(10000)
        float f = expf(nl * (float)tid / 128.0f);
        float a = (float)tt * f;
        emb[tid]       = cosf(a);
        emb[tid + 128] = sinf(a);
    }
    __syncthreads();
    float acc = bstep[tid];
    const float* wr = Wstep + tid * DD;                  // W_step[j, :]
    for (int k = 0; k < DD; ++k) acc = fmaf(emb[k], wr[k], acc);
    Temb[tt * DD + tid] = acc;
}

// ---------- t-path through layer 1: T1[1000][768] = Temb @ W1[:,512:].T + b1 ----------
__global__ void k_t1(const float* __restrict__ Temb, const float* __restrict__ W1,
                     const float* __restrict__ b1, float* __restrict__ T1) {
    __shared__ float te[DD];
    const int tt = blockIdx.x;
    const int n  = blockIdx.y * 256 + threadIdx.x;       // 0..767
    te[threadIdx.x] = Temb[tt * DD + threadIdx.x];
    __syncthreads();
    float acc = b1[n];
    const float* wr = W1 + n * D3 + KXC;                 // W1[n, 512:]
    for (int k = 0; k < DD; ++k) acc = fmaf(te[k], wr[k], acc);
    T1[tt * D3 + n] = acc;
}

// ---------- weight split: hi/lo bf16, [n][k] k-contiguous ----------
__global__ void k_cvt(const float* __restrict__ src, unsigned short* __restrict__ hi,
                      unsigned short* __restrict__ lo, int kout, int kin, int total) {
    int i = blockIdx.x * 256 + threadIdx.x;
    if (i >= total) return;
    int n = i / kout, k = i - n * kout;
    float v = src[(size_t)n * kin + k];
    unsigned short h = f2bf(v);
    hi[i] = h;
    lo[i] = f2bf(v - bf2f(h));
}

// ---------- fused main: MFMA split-bf16 ----------
__global__ __launch_bounds__(NTHR, 2)
void k_main(const float* __restrict__ x, const float* __restrict__ c,
            const int* __restrict__ t, const float* __restrict__ T1,
            const unsigned short* __restrict__ W1hi, const unsigned short* __restrict__ W1lo,
            const unsigned short* __restrict__ W2hi, const unsigned short* __restrict__ W2lo,
            const float* __restrict__ b2, float* __restrict__ out) {
    extern __shared__ __align__(16) char smem[];
    char* Ah = smem;                 // [64][512] bf16 hi, swizzled
    char* Al = smem + 65536;         // lo
    char* Hh = smem + 131072;        // [64][64] bf16 hi, swizzled
    char* Hl = smem + 139264;

    const int tid  = threadIdx.x;
    const int lane = tid & 63;
    const int wid  = tid >> 6;       // 0..7
    const int wm   = wid >> 2;       // 0..1 : row-half of block
    const int wn   = wid & 3;        // 0..3 : col group
    const int l15  = lane & 15;
    const int lk8  = (lane >> 4) * 8;    // frag k-offset
    const int lr4  = (lane >> 4) * 4;    // C-frag row base
    const int row0 = blockIdx.x * BM;

    // ---- stage A = [x|c] rows as bf16 hi/lo into LDS (once), swizzled ----
    #pragma unroll
    for (int it = 0; it < 16; ++it) {
        int q    = it * NTHR + tid;          // float4 index into [64][512]
        int row  = q >> 7;                   // 128 float4 per row
        int col4 = q & 127;
        int col  = col4 * 4;
        const float* src = (col < 256) ? &x[(size_t)(row0 + row) * DD + col]
                                       : &c[(size_t)(row0 + row) * DD + (col - 256)];
        float4 v = *(const float4*)src;
        float f[4] = {v.x, v.y, v.z, v.w};
        u16x4 h, l;
        #pragma unroll
        for (int j = 0; j < 4; ++j) {
            unsigned short hh = f2bf(f[j]);
            h[j] = hh;
            l[j] = f2bf(f[j] - bf2f(hh));
        }
        int off = row * 1024 + col4 * 8;
        int swz = off ^ ((row & 7) << 4);
        *(u16x4*)(Ah + swz) = h;
        *(u16x4*)(Al + swz) = l;
    }
    __syncthreads();

    f32x4 oacc[2][4];                        // layer-2 out tiles [mt2][nt]
    #pragma unroll
    for (int i = 0; i < 2; ++i)
        #pragma unroll
        for (int j = 0; j < 4; ++j) oacc[i][j] = (f32x4){0.f, 0.f, 0.f, 0.f};

    #pragma unroll 1
    for (int ncg = 0; ncg < 6; ++ncg) {      // pairs of 64-col chunks
        f32x4 acc1[2][2];                    // [chunk][mt]
        #pragma unroll
        for (int i = 0; i < 2; ++i)
            #pragma unroll
            for (int j = 0; j < 2; ++j) acc1[i][j] = (f32x4){0.f, 0.f, 0.f, 0.f};

        // ---- layer-1 K loop (no barriers: A is read-only in LDS) ----
        #pragma unroll 2
        for (int kt = 0; kt < 8; ++kt) {
            s16x8 ah[2][2], al[2][2];        // [mt][ks]
            #pragma unroll
            for (int mt = 0; mt < 2; ++mt)
                #pragma unroll
                for (int ks = 0; ks < 2; ++ks) {
                    int row = wm * 32 + mt * 16 + l15;
                    int off = row * 1024 + (kt * 64 + ks * 32 + lk8) * 2;
                    int swz = off ^ ((row & 7) << 4);
                    ah[mt][ks] = *(const s16x8*)(Ah + swz);
                    al[mt][ks] = *(const s16x8*)(Al + swz);
                }
            #pragma unroll
            for (int cc = 0; cc < 2; ++cc) {
                int n = (ncg * 2 + cc) * 64 + wn * 16 + l15;
                #pragma unroll
                for (int ks = 0; ks < 2; ++ks) {
                    int koff = kt * 64 + ks * 32 + lk8;
                    s16x8 bh = *(const s16x8*)(W1hi + (size_t)n * KXC + koff);
                    s16x8 bl = *(const s16x8*)(W1lo + (size_t)n * KXC + koff);
                    #pragma unroll
                    for (int mt = 0; mt < 2; ++mt) {
                        acc1[cc][mt] = __builtin_amdgcn_mfma_f32_16x16x32_bf16(al[mt][ks], bh, acc1[cc][mt], 0, 0, 0);
                        acc1[cc][mt] = __builtin_amdgcn_mfma_f32_16x16x32_bf16(ah[mt][ks], bl, acc1[cc][mt], 0, 0, 0);
                        acc1[cc][mt] = __builtin_amdgcn_mfma_f32_16x16x32_bf16(ah[mt][ks], bh, acc1[cc][mt], 0, 0, 0);
                    }
                }
            }
        }

        // ---- per chunk: epilogue -> H (LDS) -> layer-2 accumulate ----
        #pragma unroll 1
        for (int cc = 0; cc < 2; ++cc) {
            const int nc = ncg * 2 + cc;
            __syncthreads();                 // previous chunk's H reads done
            #pragma unroll
            for (int mt = 0; mt < 2; ++mt)
                #pragma unroll
                for (int j = 0; j < 4; ++j) {
                    int m = wm * 32 + mt * 16 + lr4 + j;
                    int n = nc * 64 + wn * 16 + l15;
                    float v = acc1[cc][mt][j] + T1[(size_t)t[row0 + m] * D3 + n];
                    v = v > 0.f ? v : 0.01f * v;
                    unsigned short hh = f2bf(v);
                    unsigned short ll = f2bf(v - bf2f(hh));
                    int off = m * 128 + (wn * 16 + l15) * 2;
                    int swz = off ^ ((m & 7) << 4);
                    *(unsigned short*)(Hh + swz) = hh;
                    *(unsigned short*)(Hl + swz) = ll;
                }
            __syncthreads();                 // H complete

            s16x8 hh_[2][2], hl_[2][2];      // [mt2][ks]
            #pragma unroll
            for (int mt2 = 0; mt2 < 2; ++mt2)
                #pragma unroll
                for (int ks = 0; ks < 2; ++ks) {
                    int row = wm * 32 + mt2 * 16 + l15;
                    int off = row * 128 + (ks * 32 + lk8) * 2;
                    int swz = off ^ ((row & 7) << 4);
                    hh_[mt2][ks] = *(const s16x8*)(Hh + swz);
                    hl_[mt2][ks] = *(const s16x8*)(Hl + swz);
                }
            #pragma unroll
            for (int nt = 0; nt < 4; ++nt) {
                int n2 = wn * 64 + nt * 16 + l15;
                #pragma unroll
                for (int ks = 0; ks < 2; ++ks) {
                    int k2 = nc * 64 + ks * 32 + lk8;
                    s16x8 wh = *(const s16x8*)(W2hi + (size_t)n2 * D3 + k2);
                    s16x8 wl = *(const s16x8*)(W2lo + (size_t)n2 * D3 + k2);
                    #pragma unroll
                    for (int mt2 = 0; mt2 < 2; ++mt2) {
                        oacc[mt2][nt] = __builtin_amdgcn_mfma_f32_16x16x32_bf16(hl_[mt2][ks], wh, oacc[mt2][nt], 0, 0, 0);
                        oacc[mt2][nt] = __builtin_amdgcn_mfma_f32_16x16x32_bf16(hh_[mt2][ks], wl, oacc[mt2][nt], 0, 0, 0);
                        oacc[mt2][nt] = __builtin_amdgcn_mfma_f32_16x16x32_bf16(hh_[mt2][ks], wh, oacc[mt2][nt], 0, 0, 0);
                    }
                }
            }
        }
    }

    // ---- write out + b2 ----
    float b2r[4];
    #pragma unroll
    for (int nt = 0; nt < 4; ++nt) b2r[nt] = b2[wn * 64 + nt * 16 + l15];
    #pragma unroll
    for (int mt2 = 0; mt2 < 2; ++mt2)
        #pragma unroll
        for (int j = 0; j < 4; ++j) {
            int m = row0 + wm * 32 + mt2 * 16 + lr4 + j;
            #pragma unroll
            for (int nt = 0; nt < 4; ++nt)
                out[(size_t)m * DD + wn * 64 + nt * 16 + l15] = oacc[mt2][nt][j] + b2r[nt];
        }
}

extern "C" void kernel_launch(void* const* d_in, const int* in_sizes, int n_in,
                              void* d_out, int out_size, void* d_ws, size_t ws_size,
                              hipStream_t stream) {
    const float* x     = (const float*)d_in[0];
    const float* c     = (const float*)d_in[1];
    const int*   t     = (const int*)  d_in[2];
    const float* Wstep = (const float*)d_in[3];
    const float* bstep = (const float*)d_in[4];
    const float* W1    = (const float*)d_in[5];
    const float* b1    = (const float*)d_in[6];
    const float* W2    = (const float*)d_in[7];
    const float* b2    = (const float*)d_in[8];
    float*       out   = (float*)d_out;

    const int B = in_sizes[0] / DD;          // 131072

    // ws layout (bytes), all 16-aligned:
    char* ws = (char*)d_ws;
    float*          Temb = (float*)(ws);                 // 1,024,000
    float*          T1   = (float*)(ws + 1024000);       // 3,072,000
    unsigned short* W1hi = (unsigned short*)(ws + 4096000);  // 786,432
    unsigned short* W1lo = (unsigned short*)(ws + 4882432);  // 786,432
    unsigned short* W2hi = (unsigned short*)(ws + 5668864);  // 393,216
    unsigned short* W2lo = (unsigned short*)(ws + 6062080);  // 393,216 (end 6,455,296)

    k_temb<<<MAXT, 256, 0, stream>>>(Wstep, bstep, Temb);
    k_t1<<<dim3(MAXT, 3), 256, 0, stream>>>(Temb, W1, b1, T1);
    k_cvt<<<(D3 * KXC + 255) / 256, 256, 0, stream>>>(W1, W1hi, W1lo, KXC, D3, D3 * KXC);
    k_cvt<<<(DD * D3 + 255) / 256, 256, 0, stream>>>(W2, W2hi, W2lo, D3, D3, DD * D3);

    hipFuncSetAttribute((const void*)k_main, hipFuncAttributeMaxDynamicSharedMemorySize, SMEM_BYTES);
    k_main<<<B / BM, NTHR, SMEM_BYTES, stream>>>(x, c, t, T1, W1hi, W1lo, W2hi, W2lo, b2, out);
}

// Round 3
// 1054.429 us; speedup vs baseline: 1.5240x; 1.5240x over previous
//
#include <hip/hip_runtime.h>
#include <math.h>

#define DD    256
#define D3    768
#define KXC   512
#define MAXT  1000
#define BM    64
#define NTHR  1024
#define SMEM_BYTES 163840   // Ah 64K | Al 64K | H dbuf 2x16K

using s16x8  = __attribute__((ext_vector_type(8))) short;
using f32x16 = __attribute__((ext_vector_type(16))) float;
using u16x4  = __attribute__((ext_vector_type(4))) unsigned short;

__device__ __forceinline__ unsigned short f2bf(float f) {
    union { float f; unsigned u; } v; v.f = f;
    unsigned r = v.u + 0x7fffu + ((v.u >> 16) & 1u);
    return (unsigned short)(r >> 16);
}
__device__ __forceinline__ float bf2f(unsigned short h) {
    union { unsigned u; float f; } v; v.u = ((unsigned)h) << 16;
    return v.f;
}

// ---------- timestep embedding table: Temb[1000][256] ----------
__global__ void k_temb(const float* __restrict__ Wstep, const float* __restrict__ bstep,
                       float* __restrict__ Temb) {
    __shared__ float emb[DD];
    const int tt  = blockIdx.x;
    const int tid = threadIdx.x;
    if (tid < 128) {
        const float nl = -9.210340371976184f;            // -ln(10000)
        float f = expf(nl * (float)tid / 128.0f);
        float a = (float)tt * f;
        emb[tid]       = cosf(a);
        emb[tid + 128] = sinf(a);
    }
    __syncthreads();
    float acc = bstep[tid];
    const float* wr = Wstep + tid * DD;
    for (int k = 0; k < DD; ++k) acc = fmaf(emb[k], wr[k], acc);
    Temb[tt * DD + tid] = acc;
}

// ---------- t-path through layer 1: T1[1000][768] = Temb @ W1[:,512:].T + b1 ----------
__global__ void k_t1(const float* __restrict__ Temb, const float* __restrict__ W1,
                     const float* __restrict__ b1, float* __restrict__ T1) {
    __shared__ float te[DD];
    const int tt = blockIdx.x;
    const int n  = blockIdx.y * 256 + threadIdx.x;
    te[threadIdx.x] = Temb[tt * DD + threadIdx.x];
    __syncthreads();
    float acc = b1[n];
    const float* wr = W1 + n * D3 + KXC;
    for (int k = 0; k < DD; ++k) acc = fmaf(te[k], wr[k], acc);
    T1[tt * D3 + n] = acc;
}

// ---------- W1 x|c part -> k-major frag tiles: [ks<32][n<768][h<2][8] hi/lo ----------
__global__ void k_cvtW1(const float* __restrict__ W1, unsigned short* __restrict__ hi,
                        unsigned short* __restrict__ lo) {
    int i = blockIdx.x * 256 + threadIdx.x;
    if (i >= 32 * 768 * 16) return;
    int j  = i & 7;
    int h  = (i >> 3) & 1;
    int nn = (i >> 4) % 768;
    int ks = (i >> 4) / 768;
    int k  = ks * 16 + h * 8 + j;
    float v = W1[(size_t)nn * D3 + k];
    unsigned short hh = f2bf(v);
    hi[i] = hh;
    lo[i] = f2bf(v - bf2f(hh));
}

// ---------- W2 -> k-major frag tiles: [kq<48][n<256][h<2][8] hi/lo ----------
__global__ void k_cvtW2(const float* __restrict__ W2, unsigned short* __restrict__ hi,
                        unsigned short* __restrict__ lo) {
    int i = blockIdx.x * 256 + threadIdx.x;
    if (i >= 48 * 256 * 16) return;
    int j  = i & 7;
    int h  = (i >> 3) & 1;
    int nn = (i >> 4) % 256;
    int kq = (i >> 4) / 256;
    int k  = kq * 16 + h * 8 + j;
    float v = W2[(size_t)nn * D3 + k];
    unsigned short hh = f2bf(v);
    hi[i] = hh;
    lo[i] = f2bf(v - bf2f(hh));
}

// ---------- fused main: 32x32x16 MFMA, split-bf16 3-product ----------
__global__ __launch_bounds__(NTHR, 4)
void k_main(const float* __restrict__ x, const float* __restrict__ c,
            const int* __restrict__ t, const float* __restrict__ T1,
            const unsigned short* __restrict__ W1hi, const unsigned short* __restrict__ W1lo,
            const unsigned short* __restrict__ W2hi, const unsigned short* __restrict__ W2lo,
            const float* __restrict__ b2, float* __restrict__ out) {
    extern __shared__ __align__(16) char smem[];
    char* Ah = smem;            // [ks 32][h 2][row 64][16B]
    char* Al = smem + 65536;
    // H buffers at 131072 + sb*16384 : hi [kl 4][h 2][row 64][16B], lo at +8192

    const int tid  = threadIdx.x;
    const int lane = tid & 63;
    const int wid  = tid >> 6;        // 0..15
    const int wm   = wid >> 3;        // 0..1  (row half: 32 rows)
    const int wn   = wid & 7;         // 0..7  (32-col group)
    const int l31  = lane & 31;
    const int lh   = lane >> 5;       // k-half of fragment
    const int row0 = blockIdx.x * BM;

    const s16x8* W1hiV = (const s16x8*)W1hi;
    const s16x8* W1loV = (const s16x8*)W1lo;
    const s16x8* W2hiV = (const s16x8*)W2hi;
    const s16x8* W2loV = (const s16x8*)W2lo;

    // ---- stage A = [x|c] as bf16 hi/lo frag tiles ----
    #pragma unroll
    for (int it = 0; it < 8; ++it) {
        int q    = it * NTHR + tid;          // float4 index into [64][512]
        int row  = q >> 7;
        int col4 = q & 127;
        int k    = col4 * 4;
        const float* src = (k < 256) ? &x[(size_t)(row0 + row) * DD + k]
                                     : &c[(size_t)(row0 + row) * DD + (k - 256)];
        float4 v = *(const float4*)src;
        float f[4] = {v.x, v.y, v.z, v.w};
        u16x4 hv, lv;
        #pragma unroll
        for (int j = 0; j < 4; ++j) {
            unsigned short hh = f2bf(f[j]);
            hv[j] = hh;
            lv[j] = f2bf(f[j] - bf2f(hh));
        }
        int ks = k >> 4, h = (k >> 3) & 1, pos = k & 7;
        char* dst = Ah + ((((ks * 2 + h) * 64) + row) << 4) + pos * 2;
        *(u16x4*)dst = hv;
        *(u16x4*)(dst + 65536) = lv;
    }
    __syncthreads();

    f32x16 oacc;
    #pragma unroll
    for (int r = 0; r < 16; ++r) oacc[r] = 0.f;
    const float b2r = b2[wn * 32 + l31];

    #pragma unroll 1
    for (int p = 0; p < 3; ++p) {            // 3 passes of 256 layer-1 cols
        const int c0 = p * 256 + wn * 32;    // this wave's col base

        // T1 prefetch for this wave's tile (consumed in epilogue)
        float tv[16];
        #pragma unroll
        for (int r = 0; r < 16; ++r) {
            int m = wm * 32 + (r & 3) + 8 * (r >> 2) + 4 * lh;
            tv[r] = T1[(size_t)t[row0 + m] * D3 + c0 + l31];
        }

        f32x16 acc1;
        #pragma unroll
        for (int r = 0; r < 16; ++r) acc1[r] = 0.f;

        const int nb = c0 + l31;             // global layer-1 col for B frag
        const int arow = wm * 32 + l31;

        #pragma unroll 8
        for (int ks = 0; ks < 32; ++ks) {
            const s16x8 ahf = *(const s16x8*)(Ah + ((((ks * 2 + lh) * 64) + arow) << 4));
            const s16x8 alf = *(const s16x8*)(Al + ((((ks * 2 + lh) * 64) + arow) << 4));
            const s16x8 bhf = W1hiV[(ks * D3 + nb) * 2 + lh];
            const s16x8 blf = W1loV[(ks * D3 + nb) * 2 + lh];
            acc1 = __builtin_amdgcn_mfma_f32_32x32x16_bf16(alf, bhf, acc1, 0, 0, 0);
            acc1 = __builtin_amdgcn_mfma_f32_32x32x16_bf16(ahf, blf, acc1, 0, 0, 0);
            acc1 = __builtin_amdgcn_mfma_f32_32x32x16_bf16(ahf, bhf, acc1, 0, 0, 0);
        }

        // ---- 4 sub-chunks of 64 H-cols: epilogue -> H LDS -> layer-2 ----
        #pragma unroll 1
        for (int s = 0; s < 4; ++s) {
            char* Hb = smem + 131072 + (s & 1) * 16384;   // hi at +0, lo at +8192
            if ((wn >> 1) == s) {                          // owner waves write H
                #pragma unroll
                for (int r = 0; r < 16; ++r) {
                    int m = wm * 32 + (r & 3) + 8 * (r >> 2) + 4 * lh;
                    float v = acc1[r] + tv[r];
                    v = v > 0.f ? v : 0.01f * v;
                    unsigned short hh = f2bf(v);
                    unsigned short ll = f2bf(v - bf2f(hh));
                    int cl  = (wn & 1) * 32 + l31;         // 0..63 within sub-chunk
                    int kl  = cl >> 4, hb = (cl >> 3) & 1, pos = cl & 7;
                    int off = ((((kl * 2 + hb) * 64) + m) << 4) + pos * 2;
                    *(unsigned short*)(Hb + off)        = hh;
                    *(unsigned short*)(Hb + 8192 + off) = ll;
                }
            }
            __syncthreads();
            const int kq0 = p * 16 + s * 4;
            #pragma unroll
            for (int kl = 0; kl < 4; ++kl) {
                int hoff = (((kl * 2 + lh) * 64) + arow) << 4;
                const s16x8 hhf = *(const s16x8*)(Hb + hoff);
                const s16x8 hlf = *(const s16x8*)(Hb + 8192 + hoff);
                int wi = ((kq0 + kl) * DD + wn * 32 + l31) * 2 + lh;
                const s16x8 whf = W2hiV[wi];
                const s16x8 wlf = W2loV[wi];
                oacc = __builtin_amdgcn_mfma_f32_32x32x16_bf16(hlf, whf, oacc, 0, 0, 0);
                oacc = __builtin_amdgcn_mfma_f32_32x32x16_bf16(hhf, wlf, oacc, 0, 0, 0);
                oacc = __builtin_amdgcn_mfma_f32_32x32x16_bf16(hhf, whf, oacc, 0, 0, 0);
            }
        }
    }

    // ---- write out + b2 ----
    #pragma unroll
    for (int r = 0; r < 16; ++r) {
        int m = wm * 32 + (r & 3) + 8 * (r >> 2) + 4 * lh;
        out[(size_t)(row0 + m) * DD + wn * 32 + l31] = oacc[r] + b2r;
    }
}

extern "C" void kernel_launch(void* const* d_in, const int* in_sizes, int n_in,
                              void* d_out, int out_size, void* d_ws, size_t ws_size,
                              hipStream_t stream) {
    const float* x     = (const float*)d_in[0];
    const float* c     = (const float*)d_in[1];
    const int*   t     = (const int*)  d_in[2];
    const float* Wstep = (const float*)d_in[3];
    const float* bstep = (const float*)d_in[4];
    const float* W1    = (const float*)d_in[5];
    const float* b1    = (const float*)d_in[6];
    const float* W2    = (const float*)d_in[7];
    const float* b2    = (const float*)d_in[8];
    float*       out   = (float*)d_out;

    const int B = in_sizes[0] / DD;          // 131072

    char* ws = (char*)d_ws;
    float*          Temb = (float*)(ws);                     // 1,024,000
    float*          T1   = (float*)(ws + 1024000);           // 3,072,000
    unsigned short* W1hi = (unsigned short*)(ws + 4096000);  // 786,432
    unsigned short* W1lo = (unsigned short*)(ws + 4882432);  // 786,432
    unsigned short* W2hi = (unsigned short*)(ws + 5668864);  // 393,216
    unsigned short* W2lo = (unsigned short*)(ws + 6062080);  // 393,216

    k_temb<<<MAXT, 256, 0, stream>>>(Wstep, bstep, Temb);
    k_t1<<<dim3(MAXT, 3), 256, 0, stream>>>(Temb, W1, b1, T1);
    k_cvtW1<<<(32 * 768 * 16 + 255) / 256, 256, 0, stream>>>(W1, W1hi, W1lo);
    k_cvtW2<<<(48 * 256 * 16 + 255) / 256, 256, 0, stream>>>(W2, W2hi, W2lo);

    hipFuncSetAttribute((const void*)k_main, hipFuncAttributeMaxDynamicSharedMemorySize, SMEM_BYTES);
    k_main<<<B / BM, NTHR, SMEM_BYTES, stream>>>(x, c, t, T1, W1hi, W1lo, W2hi, W2lo, b2, out);
}

// Round 5
// 957.508 us; speedup vs baseline: 1.6782x; 1.1012x over previous
//
#include <hip/hip_runtime.h>
#include <math.h>

#define DD    256
#define D3    768
#define KXC   512
#define MAXT  1000
#define BM    64
#define NTHR  512
#define SMEM_BYTES (65536 + 16384)   // A 64KB + H dbuf 2x8KB

typedef _Float16 f16;
using f16x8  = __attribute__((ext_vector_type(8))) _Float16;
using f16x4  = __attribute__((ext_vector_type(4))) _Float16;
using f32x16 = __attribute__((ext_vector_type(16))) float;

// ---------- timestep embedding table: Temb[1000][256] (fp32) ----------
__global__ void k_temb(const float* __restrict__ Wstep, const float* __restrict__ bstep,
                       float* __restrict__ Temb) {
    __shared__ float emb[DD];
    const int tt  = blockIdx.x;
    const int tid = threadIdx.x;
    if (tid < 128) {
        const float nl = -9.210340371976184f;            // -ln(10000)
        float f = expf(nl * (float)tid / 128.0f);
        float a = (float)tt * f;
        emb[tid]       = cosf(a);
        emb[tid + 128] = sinf(a);
    }
    __syncthreads();
    float acc = bstep[tid];
    const float* wr = Wstep + tid * DD;
    for (int k = 0; k < DD; ++k) acc = fmaf(emb[k], wr[k], acc);
    Temb[tt * DD + tid] = acc;
}

// ---------- t-path through layer 1: T1[1000][768] = Temb @ W1[:,512:].T + b1 (f16) ----------
__global__ void k_t1(const float* __restrict__ Temb, const float* __restrict__ W1,
                     const float* __restrict__ b1, f16* __restrict__ T1) {
    __shared__ float te[DD];
    const int tt = blockIdx.x;
    const int n  = blockIdx.y * 256 + threadIdx.x;
    te[threadIdx.x] = Temb[tt * DD + threadIdx.x];
    __syncthreads();
    float acc = b1[n];
    const float* wr = W1 + n * D3 + KXC;
    for (int k = 0; k < DD; ++k) acc = fmaf(te[k], wr[k], acc);
    T1[tt * D3 + n] = (f16)acc;
}

// ---------- W1 x|c part -> frag tiles: [ks<32][n<768][h<2][8] f16 ----------
__global__ void k_cvtW1(const float* __restrict__ W1, f16* __restrict__ Wf) {
    int i = blockIdx.x * 256 + threadIdx.x;
    if (i >= 32 * 768 * 16) return;
    int j  = i & 7;
    int h  = (i >> 3) & 1;
    int nn = (i >> 4) % 768;
    int ks = (i >> 4) / 768;
    int k  = ks * 16 + h * 8 + j;
    Wf[i] = (f16)W1[(size_t)nn * D3 + k];
}

// ---------- W2 -> frag tiles: [kq<48][n<256][h<2][8] f16 ----------
__global__ void k_cvtW2(const float* __restrict__ W2, f16* __restrict__ Wf) {
    int i = blockIdx.x * 256 + threadIdx.x;
    if (i >= 48 * 256 * 16) return;
    int j  = i & 7;
    int h  = (i >> 3) & 1;
    int nn = (i >> 4) % 256;
    int kq = (i >> 4) / 256;
    int k  = kq * 16 + h * 8 + j;
    Wf[i] = (f16)W2[(size_t)nn * D3 + k];
}

// ---------- fused main: 32x32x16 fp16 MFMA, single product ----------
__global__ __launch_bounds__(NTHR, 4)
void k_main(const float* __restrict__ x, const float* __restrict__ c,
            const int* __restrict__ t, const f16* __restrict__ T1,
            const f16* __restrict__ W1f, const f16* __restrict__ W2f,
            const float* __restrict__ b2, float* __restrict__ out) {
    extern __shared__ __align__(16) char smem[];
    char* A = smem;                  // [ks32][h2][row64][16B], full-addr XOR (ks&7)<<4
    // H buffers: smem + 65536 + (s&1)*8192 : [m64][n64 f16], XOR (m&7)<<4

    const int tid  = threadIdx.x;
    const int lane = tid & 63;
    const int wn   = tid >> 6;       // 0..7 : 32-col group
    const int l31  = lane & 31;
    const int lh   = lane >> 5;
    const int row0 = blockIdx.x * BM;

    // ---- stage A = [x|c] as f16 frag tiles (coalesced global reads) ----
    #pragma unroll
    for (int it = 0; it < 16; ++it) {
        int q    = it * NTHR + tid;          // float4 index into [64][512]
        int row  = q >> 7;
        int col4 = q & 127;
        int k    = col4 * 4;
        const float* src = (k < 256) ? &x[(size_t)(row0 + row) * DD + k]
                                     : &c[(size_t)(row0 + row) * DD + (k - 256)];
        float4 v = *(const float4*)src;
        f16x4 hv;
        hv[0] = (f16)v.x; hv[1] = (f16)v.y; hv[2] = (f16)v.z; hv[3] = (f16)v.w;
        int ks = k >> 4, h = (k >> 3) & 1, pos = k & 7;
        int off = ((((ks * 2 + h) * 64) + row) << 4) + pos * 2;
        off ^= (ks & 7) << 4;                // full-address XOR (matches reads)
        *(f16x4*)(A + off) = hv;
    }
    __syncthreads();

    f32x16 oacc[2];
    #pragma unroll
    for (int mt = 0; mt < 2; ++mt)
        #pragma unroll
        for (int r = 0; r < 16; ++r) oacc[mt][r] = 0.f;
    const float b2r = b2[wn * 32 + l31];

    const f16x8* W1v = (const f16x8*)W1f;
    const f16x8* W2v = (const f16x8*)W2f;

    const int s_own = wn >> 1;               // sub-chunk this wave owns
    const int nl    = (wn & 1) * 32 + l31;   // col within owned sub-chunk

    #pragma unroll 1
    for (int p = 0; p < 3; ++p) {            // 3 passes of 256 layer-1 cols
        // ---- prefetch T1 for owned sub-chunk (hides under K-loop) ----
        f16 tv[2][16];
        #pragma unroll
        for (int mt = 0; mt < 2; ++mt)
            #pragma unroll
            for (int r = 0; r < 16; ++r) {
                int m = mt * 32 + (r & 3) + 8 * (r >> 2) + 4 * lh;
                tv[mt][r] = T1[(size_t)t[row0 + m] * D3 + p * 256 + s_own * 64 + nl];
            }

        f32x16 acc1[2];
        #pragma unroll
        for (int mt = 0; mt < 2; ++mt)
            #pragma unroll
            for (int r = 0; r < 16; ++r) acc1[mt][r] = 0.f;

        const int nb = p * 256 + wn * 32 + l31;   // this lane's layer-1 col

        #pragma unroll 4
        for (int ks = 0; ks < 32; ++ks) {
            const f16x8 b = W1v[(ks * D3 + nb) * 2 + lh];
            const int key = (ks & 7) << 4;
            int off0 = ((((ks * 2 + lh) * 64) + l31) << 4) ^ key;
            int off1 = ((((ks * 2 + lh) * 64) + 32 + l31) << 4) ^ key;
            const f16x8 a0 = *(const f16x8*)(A + off0);
            const f16x8 a1 = *(const f16x8*)(A + off1);
            acc1[0] = __builtin_amdgcn_mfma_f32_32x32x16_f16(a0, b, acc1[0], 0, 0, 0);
            acc1[1] = __builtin_amdgcn_mfma_f32_32x32x16_f16(a1, b, acc1[1], 0, 0, 0);
        }

        // ---- 4 sub-chunks of 64 H-cols: epilogue -> H LDS -> layer-2 ----
        #pragma unroll 1
        for (int s = 0; s < 4; ++s) {
            char* Hb = smem + 65536 + (s & 1) * 8192;
            if (s_own == s) {                         // owners: wn = 2s, 2s+1
                #pragma unroll
                for (int mt = 0; mt < 2; ++mt)
                    #pragma unroll
                    for (int r = 0; r < 16; ++r) {
                        int m = mt * 32 + (r & 3) + 8 * (r >> 2) + 4 * lh;
                        float v = acc1[mt][r] + (float)tv[mt][r];
                        v = v > 0.f ? v : 0.01f * v;
                        int off = ((m << 7) + nl * 2) ^ ((m & 7) << 4);
                        *(f16*)(Hb + off) = (f16)v;
                    }
            }
            __syncthreads();
            const int kq0 = p * 16 + s * 4;
            #pragma unroll
            for (int q = 0; q < 4; ++q) {
                const f16x8 w = W2v[((kq0 + q) * DD + wn * 32 + l31) * 2 + lh];
                #pragma unroll
                for (int mt = 0; mt < 2; ++mt) {
                    int m = mt * 32 + l31;
                    int off = ((m << 7) + q * 32 + lh * 16) ^ ((m & 7) << 4);
                    const f16x8 hf = *(const f16x8*)(Hb + off);
                    oacc[mt] = __builtin_amdgcn_mfma_f32_32x32x16_f16(hf, w, oacc[mt], 0, 0, 0);
                }
            }
        }
    }

    // ---- write out + b2 (coalesced 128B runs) ----
    #pragma unroll
    for (int mt = 0; mt < 2; ++mt)
        #pragma unroll
        for (int r = 0; r < 16; ++r) {
            int m = mt * 32 + (r & 3) + 8 * (r >> 2) + 4 * lh;
            out[(size_t)(row0 + m) * DD + wn * 32 + l31] = oacc[mt][r] + b2r;
        }
}

extern "C" void kernel_launch(void* const* d_in, const int* in_sizes, int n_in,
                              void* d_out, int out_size, void* d_ws, size_t ws_size,
                              hipStream_t stream) {
    const float* x     = (const float*)d_in[0];
    const float* c     = (const float*)d_in[1];
    const int*   t     = (const int*)  d_in[2];
    const float* Wstep = (const float*)d_in[3];
    const float* bstep = (const float*)d_in[4];
    const float* W1    = (const float*)d_in[5];
    const float* b1    = (const float*)d_in[6];
    const float* W2    = (const float*)d_in[7];
    const float* b2    = (const float*)d_in[8];
    float*       out   = (float*)d_out;

    const int B = in_sizes[0] / DD;          // 131072

    // ws layout (bytes, 16-aligned): Temb fp32 | T1 f16 | W1f f16 | W2f f16
    char* ws = (char*)d_ws;
    float* Temb = (float*)(ws);                  // 1,024,000
    f16*   T1   = (f16*)(ws + 1024000);          // 1,536,000
    f16*   W1f  = (f16*)(ws + 2560000);          //   786,432
    f16*   W2f  = (f16*)(ws + 3346432);          //   393,216 (end 3,739,648)

    k_temb<<<MAXT, 256, 0, stream>>>(Wstep, bstep, Temb);
    k_t1<<<dim3(MAXT, 3), 256, 0, stream>>>(Temb, W1, b1, T1);
    k_cvtW1<<<(32 * 768 * 16 + 255) / 256, 256, 0, stream>>>(W1, W1f);
    k_cvtW2<<<(48 * 256 * 16 + 255) / 256, 256, 0, stream>>>(W2, W2f);

    hipFuncSetAttribute((const void*)k_main, hipFuncAttributeMaxDynamicSharedMemorySize, SMEM_BYTES);
    k_main<<<B / BM, NTHR, SMEM_BYTES, stream>>>(x, c, t, T1, W1f, W2f, b2, out);
}